// Round 1
// baseline (1687.515 us; speedup 1.0000x reference)
//
#include <hip/hip_runtime.h>

#define H 128
#define RT 4  // rows (nodes/edges) per wave-iteration

// ---------------------------------------------------------------------------
// Node projection: P[y][n][:] = NF[n] @ W_y  (+ b if y==1)
// W_y = rows [y*128, y*128+128) of W (row-major [384][128])
// ---------------------------------------------------------------------------
__global__ __launch_bounds__(512, 4)
void node_proj_kernel(const float* __restrict__ nf, const float* __restrict__ W,
                      const float* __restrict__ b, float* __restrict__ P,
                      int n_nodes) {
    __shared__ float Wlds[H * H];  // 64 KB
    const int y = blockIdx.y;
    const float* Wsrc = W + (size_t)y * H * H;
    for (int i = threadIdx.x; i < H * H / 4; i += blockDim.x)
        ((float4*)Wlds)[i] = ((const float4*)Wsrc)[i];
    __syncthreads();

    const int lane = threadIdx.x & 63;
    const int wv = threadIdx.x >> 6;
    const int kk = lane >> 5;    // which k-parity half this lane handles
    const int c32 = lane & 31;   // 4-col group
    const int waves_per_blk = blockDim.x >> 6;
    const int wid = blockIdx.x * waves_per_blk + wv;
    const int nwaves = gridDim.x * waves_per_blk;
    const int ntiles = (n_nodes + RT - 1) / RT;
    float* Pout = P + (size_t)y * n_nodes * H;

    for (int t = wid; t < ntiles; t += nwaves) {
        const int row0 = t * RT;
        float4 acc[RT];
#pragma unroll
        for (int r = 0; r < RT; ++r) acc[r] = make_float4(0.f, 0.f, 0.f, 0.f);

        const float* rp[RT];
#pragma unroll
        for (int r = 0; r < RT; ++r) {
            int rr = row0 + r;
            rp[r] = nf + (size_t)(rr < n_nodes ? rr : 0) * H;
        }

#pragma unroll 4
        for (int k0 = 0; k0 < H; k0 += 2) {
            float4 w4 = *(const float4*)&Wlds[(k0 + kk) * H + 4 * c32];
#pragma unroll
            for (int r = 0; r < RT; ++r) {
                float2 x2 = *(const float2*)(rp[r] + k0);
                float x = kk ? x2.y : x2.x;
                acc[r].x += x * w4.x;
                acc[r].y += x * w4.y;
                acc[r].z += x * w4.z;
                acc[r].w += x * w4.w;
            }
        }

#pragma unroll
        for (int r = 0; r < RT; ++r) {
            acc[r].x += __shfl_xor(acc[r].x, 32, 64);
            acc[r].y += __shfl_xor(acc[r].y, 32, 64);
            acc[r].z += __shfl_xor(acc[r].z, 32, 64);
            acc[r].w += __shfl_xor(acc[r].w, 32, 64);
        }

        if (kk == 0) {
            float4 b4 = make_float4(0.f, 0.f, 0.f, 0.f);
            if (y == 1) b4 = ((const float4*)b)[c32];
#pragma unroll
            for (int r = 0; r < RT; ++r) {
                int rr = row0 + r;
                if (rr < n_nodes) {
                    float4 v = acc[r];
                    v.x += b4.x; v.y += b4.y; v.z += b4.z; v.w += b4.w;
                    *(float4*)&Pout[(size_t)rr * H + 4 * c32] = v;
                }
            }
        }
    }
}

// ---------------------------------------------------------------------------
// Edge kernel: m = relu(P1[s] + P2[r] + EF[e] @ W3); atomicAdd into out[r]
// ---------------------------------------------------------------------------
__global__ __launch_bounds__(512, 4)
void edge_kernel(const float* __restrict__ ef, const int* __restrict__ senders,
                 const int* __restrict__ receivers, const float* __restrict__ W,
                 const float* __restrict__ P, float* __restrict__ out,
                 int n_edges, int n_nodes) {
    __shared__ float Wlds[H * H];  // 64 KB: W3 = rows 256..383 of W
    const float* Wsrc = W + (size_t)2 * H * H;
    for (int i = threadIdx.x; i < H * H / 4; i += blockDim.x)
        ((float4*)Wlds)[i] = ((const float4*)Wsrc)[i];
    __syncthreads();

    const int lane = threadIdx.x & 63;
    const int wv = threadIdx.x >> 6;
    const int kk = lane >> 5;
    const int c32 = lane & 31;
    const int waves_per_blk = blockDim.x >> 6;
    const int wid = blockIdx.x * waves_per_blk + wv;
    const int nwaves = gridDim.x * waves_per_blk;
    const int ntiles = (n_edges + RT - 1) / RT;

    const float* P1 = P;
    const float* P2 = P + (size_t)n_nodes * H;

    for (int t = wid; t < ntiles; t += nwaves) {
        const int row0 = t * RT;
        int se[RT], re[RT];
#pragma unroll
        for (int r = 0; r < RT; ++r) {
            int e = row0 + r;
            int ec = e < n_edges ? e : 0;
            se[r] = senders[ec];
            re[r] = receivers[ec];
        }
        const float* rp[RT];
#pragma unroll
        for (int r = 0; r < RT; ++r) {
            int e = row0 + r;
            rp[r] = ef + (size_t)(e < n_edges ? e : 0) * H;
        }

        float4 acc[RT];
#pragma unroll
        for (int r = 0; r < RT; ++r) acc[r] = make_float4(0.f, 0.f, 0.f, 0.f);

#pragma unroll 4
        for (int k0 = 0; k0 < H; k0 += 2) {
            float4 w4 = *(const float4*)&Wlds[(k0 + kk) * H + 4 * c32];
#pragma unroll
            for (int r = 0; r < RT; ++r) {
                float2 x2 = *(const float2*)(rp[r] + k0);
                float x = kk ? x2.y : x2.x;
                acc[r].x += x * w4.x;
                acc[r].y += x * w4.y;
                acc[r].z += x * w4.z;
                acc[r].w += x * w4.w;
            }
        }

#pragma unroll
        for (int r = 0; r < RT; ++r) {
            acc[r].x += __shfl_xor(acc[r].x, 32, 64);
            acc[r].y += __shfl_xor(acc[r].y, 32, 64);
            acc[r].z += __shfl_xor(acc[r].z, 32, 64);
            acc[r].w += __shfl_xor(acc[r].w, 32, 64);
        }

        if (kk == 0) {
#pragma unroll
            for (int r = 0; r < RT; ++r) {
                int e = row0 + r;
                if (e < n_edges) {
                    const float4 p1 = *(const float4*)&P1[(size_t)se[r] * H + 4 * c32];
                    const float4 p2 = *(const float4*)&P2[(size_t)re[r] * H + 4 * c32];
                    float4 m;
                    m.x = fmaxf(acc[r].x + p1.x + p2.x, 0.f);
                    m.y = fmaxf(acc[r].y + p1.y + p2.y, 0.f);
                    m.z = fmaxf(acc[r].z + p1.z + p2.z, 0.f);
                    m.w = fmaxf(acc[r].w + p1.w + p2.w, 0.f);
                    float* dst = out + (size_t)re[r] * H + 4 * c32;
                    atomicAdd(dst + 0, m.x);
                    atomicAdd(dst + 1, m.y);
                    atomicAdd(dst + 2, m.z);
                    atomicAdd(dst + 3, m.w);
                }
            }
        }
    }
}

// ---------------------------------------------------------------------------
// Fallback (only if workspace too small): fully naive edge pass
// ---------------------------------------------------------------------------
__global__ void naive_edge_kernel(const float* __restrict__ nf, const int* __restrict__ s,
                                  const int* __restrict__ r, const float* __restrict__ ef,
                                  const float* __restrict__ W, const float* __restrict__ b,
                                  float* __restrict__ out, int n_edges) {
    int e = blockIdx.x * 2 + (threadIdx.x >> 7);
    int c = threadIdx.x & 127;
    if (e >= n_edges) return;
    int se = s[e], re = r[e];
    float acc = b[c];
    for (int k = 0; k < H; ++k) {
        acc += nf[(size_t)se * H + k] * W[(size_t)k * H + c];
        acc += nf[(size_t)re * H + k] * W[(size_t)(H + k) * H + c];
        acc += ef[(size_t)e * H + k] * W[(size_t)(2 * H + k) * H + c];
    }
    atomicAdd(&out[(size_t)re * H + c], fmaxf(acc, 0.f));
}

// ---------------------------------------------------------------------------
// LayerNorm(nf + aggr) in-place on out
// ---------------------------------------------------------------------------
__global__ __launch_bounds__(256, 4)
void ln_kernel(const float* __restrict__ nf, const float* __restrict__ lnw,
               const float* __restrict__ lnb, float* __restrict__ out, int n_nodes) {
    const int wv = threadIdx.x >> 6;
    const int lane = threadIdx.x & 63;
    const int row = blockIdx.x * (blockDim.x >> 6) + wv;
    if (row >= n_nodes) return;
    float2 a = ((const float2*)(nf + (size_t)row * H))[lane];
    float2 g = ((float2*)(out + (size_t)row * H))[lane];
    float vx = a.x + g.x, vy = a.y + g.y;

    float s = vx + vy;
#pragma unroll
    for (int m = 32; m; m >>= 1) s += __shfl_xor(s, m, 64);
    float mu = s * (1.f / H);
    float dx = vx - mu, dy = vy - mu;
    float q = dx * dx + dy * dy;
#pragma unroll
    for (int m = 32; m; m >>= 1) q += __shfl_xor(q, m, 64);
    float rs = rsqrtf(q * (1.f / H) + 1e-5f);

    float2 w2 = ((const float2*)lnw)[lane];
    float2 b2 = ((const float2*)lnb)[lane];
    float2 o;
    o.x = dx * rs * w2.x + b2.x;
    o.y = dy * rs * w2.y + b2.y;
    ((float2*)(out + (size_t)row * H))[lane] = o;
}

// ---------------------------------------------------------------------------
extern "C" void kernel_launch(void* const* d_in, const int* in_sizes, int n_in,
                              void* d_out, int out_size, void* d_ws, size_t ws_size,
                              hipStream_t stream) {
    const float* nf        = (const float*)d_in[0];
    const int*   senders   = (const int*)d_in[1];
    const int*   receivers = (const int*)d_in[2];
    const float* ef        = (const float*)d_in[3];
    const float* W         = (const float*)d_in[4];
    const float* b         = (const float*)d_in[5];
    const float* lnw       = (const float*)d_in[6];
    const float* lnb       = (const float*)d_in[7];
    float* out = (float*)d_out;

    const int n_nodes = in_sizes[0] / H;  // 50000
    const int n_edges = in_sizes[1];      // 800000

    hipMemsetAsync(d_out, 0, (size_t)n_nodes * H * sizeof(float), stream);

    const size_t need = (size_t)2 * n_nodes * H * sizeof(float);
    if (ws_size >= need) {
        float* P = (float*)d_ws;
        node_proj_kernel<<<dim3(256, 2), 512, 0, stream>>>(nf, W, b, P, n_nodes);
        edge_kernel<<<512, 512, 0, stream>>>(ef, senders, receivers, W, P, out,
                                             n_edges, n_nodes);
    } else {
        naive_edge_kernel<<<(n_edges + 1) / 2, 256, 0, stream>>>(
            nf, senders, receivers, ef, W, b, out, n_edges);
    }

    ln_kernel<<<(n_nodes + 3) / 4, 256, 0, stream>>>(nf, lnw, lnb, out, n_nodes);
}